// Round 7
// baseline (804.758 us; speedup 1.0000x reference)
//
#include <hip/hip_runtime.h>

// R11: split-transition software pipelining on R10. Budget analysis: issue
// ~860 cy/stage vs 1813 measured -> ~950 cy exposed stalls. The sig->MFMA
// boundaries serialize: both halves of each sigma transition were issued
// back-to-back, leaving the second half's ~145 cy of transcendental work
// exposed on the chain. R11 source-orders each stage as:
//   L1-f0 MFMAs x4 -> L1-f1 MFMAs x4 -> sig(g0) -> L2-g0 MFMAs x4 ->
//   sig(g1) -> L2-g1 MFMAs x4 -> sig(h0) -> L3-h0 MFMA -> sig(h1) ->
//   L3-h1 MFMA -> permlane gather -> + fg
// Per-tile accumulation order unchanged (b + W0*g0 then + W1*g1) -> every
// dot product bit-identical. px (pkrtz of x) hoisted to caller; stage 1
// reuses XC (same bits).
// Carried: ext-vector SSA state (no allocas -> no LDS/scratch); pi channel
// permutation (register-local transitions); permlane16_swap layer-3 gather;
// sigma-folding tanh(a)=1-2*sigma(2a) with -2, 2*log2(e) in weights/biases;
// fg_eval issued first (overlaps NN); f8_t pk-math; absmax must stay
// exactly 0.015625.

typedef _Float16 h2_t __attribute__((ext_vector_type(2)));
typedef _Float16 h8_t __attribute__((ext_vector_type(8)));
typedef __fp16  pk2_t __attribute__((ext_vector_type(2)));
typedef float f4_t __attribute__((ext_vector_type(4)));
typedef float f8_t __attribute__((ext_vector_type(8)));
typedef int   i4_t __attribute__((ext_vector_type(4)));

union H2I { h2_t h; pk2_t p; int i; float _f; };

#define DEVI __device__ __forceinline__

DEVI float rcp_f(float x) { return __builtin_amdgcn_rcpf(x); }
#if __has_builtin(__builtin_amdgcn_exp2f)
DEVI float exp2_f(float x) { return __builtin_amdgcn_exp2f(x); }
#else
DEVI float exp2_f(float x) { return __expf(x * 0.69314718056f); }
#endif
DEVI int pkrtz_i(float a, float b) { H2I u; u.p = __builtin_amdgcn_cvt_pkrtz(a, b); return u.i; }
DEVI int h2i(h2_t h) { H2I u; u.h = h; return u.i; }
DEVI h2_t i2h(int i) { H2I u; u.i = i; return u.h; }

#if __has_builtin(__builtin_elementwise_fma)
DEVI f8_t fma8(f8_t a, f8_t b, f8_t c) { return __builtin_elementwise_fma(a, b, c); }
#else
DEVI f8_t fma8(f8_t a, f8_t b, f8_t c) {
    f8_t r;
#pragma unroll
    for (int i = 0; i < 8; ++i) r[i] = fmaf(a[i], b[i], c[i]);
    return r;
}
#endif
DEVI f8_t splat8(float v) { f8_t r = { v, v, v, v, v, v, v, v }; return r; }

DEVI f4_t mfma16(h8_t a, h8_t b, f4_t c) {
    return __builtin_amdgcn_mfma_f32_16x16x32_f16(a, b, c, 0, 0, 0);
}

// hidden-channel permutation: physical channel computed at A-tile ct, row rho
DEVI int chan_of(int ct, int rho) {
    int qr = rho >> 2, rr = rho & 3;
    return (ct < 2) ? (8 * qr + 4 * ct + rr)
                    : (32 + 8 * qr + 4 * (ct - 2) + rr);
}

// grey-box CSTR+flash RHS, scaled coords, per-lane (batch = lane&15)
DEVI f8_t fg_eval(f8_t x, float F, float D) {
    const f8_t ystd  = { 0.3f, 0.2f, 0.2f, 5.0f, 0.3f, 0.2f, 0.2f, 5.0f };
    const f8_t ymean = { 0.7f, 0.5f, 0.5f, 310.0f, 0.7f, 0.5f, 0.5f, 310.0f };
    f8_t xs = fma8(x, ystd, ymean);

    float Hr  = xs[0], CAr = xs[1], CBr = xs[2], Tr = xs[3];
    float Hb  = xs[4], CAb = xs[5], CBb = xs[6], Tb = xs[7];

    float aA = 3.5f * CAb, aB = 1.1f * CBb;
    float rden = rcp_f(aA + aB);
    float CAd = aA * rden, CBd = aB * rden;
    float Fr = __builtin_amdgcn_sqrtf(Hr);
    float Fb = __builtin_amdgcn_sqrtf(Hb);
    float rTr = rcp_f(Tr);
    float k1v = 20000.0f * __expf(-3000.0f * rTr);
    float r1 = k1v * CAr;
    float rHr = rcp_f(Hr), rHb = rcp_f(Hb);

    f8_t d;
    d[0] = F + D - Fr;
    d[1] = (F * (1.0f - CAr) + D * (CAd - CAr)) * rHr - r1;
    d[2] = (D * (CBd - CBr) - F * CBr) * rHr + r1;
    d[3] = (F * (320.0f - Tr) + D * (310.0f - Tr)) * rHr
         - (40.0f / 3.0f) * rHr + (2.0f / 3.0f) * r1;
    d[4] = Fr - Fb - D;
    d[5] = (Fr * (CAr - CAb) + D * (CAb - CAd)) * rHb;
    d[6] = (Fr * (CBr - CBb) + D * (CBb - CBd)) * rHb;
    d[7] = Fr * (Tr - Tb) * rHb + (40.0f / 3.0f) * rHb;

    const f8_t sc = { 10.0f / 3.0f, 5.0f, 5.0f, 0.2f,
                      10.0f / 3.0f, 5.0f, 5.0f, 0.2f };
    return d * sc;
}

struct Weights {
    h8_t a1[4][2], a2[4][2], a3[2];
    f4_t b1f[4], b2f[4], b3f;
};

DEVI int sigpair(float a, float b) {
    float s0 = rcp_f(1.0f + exp2_f(a));
    float s1 = rcp_f(1.0f + exp2_f(b));
    return pkrtz_i(s0, s1);
}

// sigma transition for two C-tiles -> one B-frag (register-local, SSA)
DEVI h8_t sig4(f4_t a0, f4_t a1) {
    i4_t g;
    g[0] = sigpair(a0[0], a0[1]);
    g[1] = sigpair(a0[2], a0[3]);
    g[2] = sigpair(a1[0], a1[1]);
    g[3] = sigpair(a1[2], a1[3]);
    return __builtin_bit_cast(h8_t, g);
}

// packed-f16 midpoint of 4 pairs: (a+b)*0.5h, same rounding as before
DEVI i4_t avg4(i4_t A, i4_t B) {
    const h2_t half2c = { (_Float16)0.5f, (_Float16)0.5f };
    i4_t r;
#pragma unroll
    for (int i = 0; i < 4; ++i)
        r[i] = h2i((i2h(A[i]) + i2h(B[i])) * half2c);
    return r;
}

// f0 y-part select: quad q picks its 4 pair-words of the variant
DEVI i4_t sel_f0y(i4_t V0, i4_t V1, i4_t V2, int q) {
    i4_t r;
#pragma unroll
    for (int i = 0; i < 4; ++i) {
        int t = (q == 2) ? V1[i] : V2[i];
        r[i] = (q == 1) ? V0[i] : t;
    }
    return r;
}
// f1 select: q0 lanes get variant pairs 12..15, others the common u-part
DEVI i4_t sel_f1(i4_t V3, i4_t f1c, int q) {
    i4_t r;
#pragma unroll
    for (int i = 0; i < 4; ++i)
        r[i] = (q == 0) ? V3[i] : f1c[i];
    return r;
}

// one RK slope: k = fg(x,u) + fnn([x, zvariant, u]). px = pkrtz'd x pairs
// (precomputed by caller). Software-pipelined: each sigma half converts
// while the other half's MFMAs run.
DEVI f8_t eval_stage(f8_t x, i4_t px, i4_t f0y, i4_t f1w,
                     float F, float D, const Weights& W, int q) {
    f8_t kfg = fg_eval(x, F, D);            // independent of the NN below

    i4_t f0w;
#pragma unroll
    for (int i = 0; i < 4; ++i)
        f0w[i] = (q == 0) ? px[i] : f0y[i];
    h8_t f0 = __builtin_bit_cast(h8_t, f0w);
    h8_t f1 = __builtin_bit_cast(h8_t, f1w);

    // ---- layer 1: f0-half x4 (independent), then f1-half x4 ----
    f4_t a0 = mfma16(W.a1[0][0], f0, W.b1f[0]);
    f4_t a1 = mfma16(W.a1[1][0], f0, W.b1f[1]);
    f4_t a2 = mfma16(W.a1[2][0], f0, W.b1f[2]);
    f4_t a3 = mfma16(W.a1[3][0], f0, W.b1f[3]);
    a0 = mfma16(W.a1[0][1], f1, a0);
    a1 = mfma16(W.a1[1][1], f1, a1);
    a2 = mfma16(W.a1[2][1], f1, a2);
    a3 = mfma16(W.a1[3][1], f1, a3);

    // ---- transition 1 split: sig(g0) || L2-g0, sig(g1) || L2-g1 ----
    h8_t g0 = sig4(a0, a1);
    f4_t c0 = mfma16(W.a2[0][0], g0, W.b2f[0]);
    f4_t c1 = mfma16(W.a2[1][0], g0, W.b2f[1]);
    f4_t c2 = mfma16(W.a2[2][0], g0, W.b2f[2]);
    f4_t c3 = mfma16(W.a2[3][0], g0, W.b2f[3]);
    h8_t g1 = sig4(a2, a3);
    c0 = mfma16(W.a2[0][1], g1, c0);
    c1 = mfma16(W.a2[1][1], g1, c1);
    c2 = mfma16(W.a2[2][1], g1, c2);
    c3 = mfma16(W.a2[3][1], g1, c3);

    // ---- transition 2 split: sig(h0) || L3-h0, sig(h1) || L3-h1 ----
    h8_t h0 = sig4(c0, c1);
    f4_t acc3 = mfma16(W.a3[0], h0, W.b3f);
    h8_t h1 = sig4(c2, c3);
    acc3 = mfma16(W.a3[1], h1, acc3);

    // gather: acc3 reg r holds [ch r, ch 4+r, ch r, ch 4+r] across 16-lane
    // groups; self permlane16_swap -> ch r and ch 4+r on every lane.
    f8_t nn;
#pragma unroll
    for (int r = 0; r < 4; ++r) {
        int e = __float_as_int(acc3[r]);
        int o = e;
        asm("v_permlane16_swap_b32 %0, %1" : "+v"(e), "+v"(o));
        nn[r]     = __int_as_float(e);
        nn[4 + r] = __int_as_float(o);
    }

    return kfg + nn;
}

DEVI i4_t pack_pairs(f8_t x) {
    i4_t r;
#pragma unroll
    for (int i = 0; i < 4; ++i) r[i] = pkrtz_i(x[2 * i], x[2 * i + 1]);
    return r;
}

__global__ __launch_bounds__(64, 1)
void cstr_mfma1_kernel(const float* __restrict__ useq, const float* __restrict__ xGz0,
                       const float* __restrict__ W1, const float* __restrict__ b1,
                       const float* __restrict__ W2, const float* __restrict__ b2,
                       const float* __restrict__ W3, const float* __restrict__ b3,
                       float* __restrict__ out)
{
    const int lane = threadIdx.x & 63;
    const int m16 = lane & 15, q = lane >> 4;
    const int b0 = blockIdx.x * 16;

    const float S1 = 2.0f * 1.4426950408889634f;   // 2*log2(e)

    // ---- preload weights (sigma-folded, pi-permuted output columns) ----
    Weights W;
#pragma unroll
    for (int ct = 0; ct < 4; ++ct) {
        const int n = chan_of(ct, m16);            // A-frag row m16 -> channel
#pragma unroll
        for (int kh = 0; kh < 2; ++kh) {
            i4_t w1f, w2f;
#pragma unroll
            for (int jj = 0; jj < 4; ++jj) {
                int k0 = 32 * kh + 8 * q + 2 * jj;
                int k1 = k0 + 1;
                float v1a = (k0 < 50) ? S1 * W1[k0 * 64 + n] : 0.0f;
                float v1b = (k1 < 50) ? S1 * W1[k1 * 64 + n] : 0.0f;
                float v2a = -2.0f * S1 * W2[k0 * 64 + n];
                float v2b = -2.0f * S1 * W2[k1 * 64 + n];
                w1f[jj] = pkrtz_i(v1a, v1b);
                w2f[jj] = pkrtz_i(v2a, v2b);
            }
            W.a1[ct][kh] = __builtin_bit_cast(h8_t, w1f);
            W.a2[ct][kh] = __builtin_bit_cast(h8_t, w2f);
        }
        f4_t bb1, bb2;
#pragma unroll
        for (int r = 0; r < 4; ++r) {
            int ch = chan_of(ct, 4 * q + r);       // C slot (ct,q,r) -> channel
            bb1[r] = S1 * b1[ch];
            float cs = 0.0f;
            for (int j = 0; j < 64; ++j) cs += W2[j * 64 + ch];
            bb2[r] = S1 * (b2[ch] + cs);
        }
        W.b1f[ct] = bb1;
        W.b2f[ct] = bb2;
    }
    // layer 3: duplicate channels into rows 8-15 (ch = row&7) for the
    // permlane gather; duplicated rows are identical independent dots.
#pragma unroll
    for (int kh = 0; kh < 2; ++kh) {
        i4_t w3f;
#pragma unroll
        for (int jj = 0; jj < 4; ++jj) {
            int k0 = 32 * kh + 8 * q + 2 * jj;
            float va = -2.0f * W3[k0 * 8 + (m16 & 7)];
            float vb = -2.0f * W3[(k0 + 1) * 8 + (m16 & 7)];
            w3f[jj] = pkrtz_i(va, vb);
        }
        W.a3[kh] = __builtin_bit_cast(h8_t, w3f);
    }
    {
        f4_t bb3;
#pragma unroll
        for (int r = 0; r < 4; ++r) {
            int c = (4 * q + r) & 7;
            float cs = 0.0f;
            for (int j = 0; j < 64; ++j) cs += W3[j * 8 + c];
            bb3[r] = b3[c] + cs;
        }
        W.b3f = bb3;
    }

    // ---- per-batch state (batch = lane&15; replicated across quads) ----
    const float* xz = xGz0 + (size_t)(b0 + m16) * 48;
    f8_t xg;
#pragma unroll
    for (int c = 0; c < 8; ++c) xg[c] = xz[c];
    // y-ring as packed h2 pair-words: P0=pairs0-3, P1=4-7, P2=8-11, P3=12-15
    i4_t P0, P1, P2, P3, U;
#pragma unroll
    for (int i = 0; i < 4; ++i) {
        P0[i] = pkrtz_i(xz[ 8 + 2 * i], xz[ 9 + 2 * i]);
        P1[i] = pkrtz_i(xz[16 + 2 * i], xz[17 + 2 * i]);
        P2[i] = pkrtz_i(xz[24 + 2 * i], xz[25 + 2 * i]);
        P3[i] = pkrtz_i(xz[32 + 2 * i], xz[33 + 2 * i]);
        U[i]  = pkrtz_i(xz[40 + 2 * i], xz[41 + 2 * i]);
    }

    const float2* ur = (const float2*)(useq + (size_t)(b0 + m16) * 512);
    float2* ow = (float2*)(out + (size_t)(b0 + m16) * 2048) + q;

    float2 uu = ur[0];                      // u for t=0

    const f8_t c005  = splat8(0.005f);
    const f8_t c01   = splat8(0.01f);
    const f8_t c2    = splat8(2.0f);
    const f8_t cD6   = splat8(0.0016666667f);   // DELTA/6

#pragma unroll 1
    for (int t = 0; t < 256; ++t) {
        // prefetch next step's u (wraps harmlessly at t=255)
        const float2 uun = ur[(t + 1) & 255];

        // ---- store y_t = xG early (pre-update; fire-and-forget) ----
        {
            float s0 = (q == 0) ? xg[0] : (q == 1) ? xg[2] : (q == 2) ? xg[4] : xg[6];
            float s1 = (q == 0) ? xg[1] : (q == 1) ? xg[3] : (q == 2) ? xg[5] : xg[7];
            float2 st = { s0, s1 };
            ow[t * 4] = st;
        }

        const float u0 = uu.x, u1 = uu.y;
        const float F = fmaf(u0, 0.1f, 1.0f);
        const float D = fmaf(u1, 0.05f, 0.5f);
        const int upair_i = pkrtz_i(u0, u1);

        // xG pairs (pc[16..19]); also the px for stage 1
        i4_t XC = pack_pairs(xg);

        // variant B (midpoint) pair-words
        i4_t B0 = avg4(P0, P1), B1 = avg4(P1, P2),
             B2 = avg4(P2, P3), B3 = avg4(P3, XC);

        // common u-part of f1
        i4_t f1c;
#pragma unroll
        for (int i = 0; i < 4; ++i) {
            int t0 = (i == 0) ? ((q == 2) ? upair_i : 0) : 0;
            f1c[i] = (q == 1) ? U[i] : t0;
        }

        // stage-invariant frag words (all SSA)
        i4_t f0yA = sel_f0y(P0, P1, P2, q), f1A = sel_f1(P3, f1c, q);
        i4_t f0yB = sel_f0y(B0, B1, B2, q), f1B = sel_f1(B3, f1c, q);
        i4_t f0yC = sel_f0y(P1, P2, P3, q), f1C = sel_f1(XC, f1c, q);

        // ---- RK4 (all register-local; no LDS, no DS, no barriers) ----
        f8_t kc, ks, xv;
        kc = eval_stage(xg, XC, f0yA, f1A, F, D, W, q);
        ks = kc;
        xv = fma8(c005, kc, xg);
        kc = eval_stage(xv, pack_pairs(xv), f0yB, f1B, F, D, W, q);
        ks = fma8(c2, kc, ks);
        xv = fma8(c005, kc, xg);
        kc = eval_stage(xv, pack_pairs(xv), f0yB, f1B, F, D, W, q);
        ks = fma8(c2, kc, ks);
        xv = fma8(c01, kc, xg);
        kc = eval_stage(xv, pack_pairs(xv), f0yC, f1C, F, D, W, q);

        // ---- state update ----
        ks = ks + kc;
        xg = fma8(cD6, ks, xg);

        // y-ring shift: pure register renaming
        P0 = P1; P1 = P2; P2 = P3; P3 = XC;
        // u shift register
        {
            i4_t Un;
            Un[0] = U[1]; Un[1] = U[2]; Un[2] = U[3]; Un[3] = upair_i;
            U = Un;
        }

        uu = uun;
    }
}

extern "C" void kernel_launch(void* const* d_in, const int* in_sizes, int n_in,
                              void* d_out, int out_size, void* d_ws, size_t ws_size,
                              hipStream_t stream) {
    const float* useq = (const float*)d_in[0];
    const float* xGz0 = (const float*)d_in[1];
    const float* W1   = (const float*)d_in[2];
    const float* b1   = (const float*)d_in[3];
    const float* W2   = (const float*)d_in[4];
    const float* b2   = (const float*)d_in[5];
    const float* W3   = (const float*)d_in[6];
    const float* b3   = (const float*)d_in[7];
    float* out = (float*)d_out;

    // 8192 batch / 16 per group = 512 blocks of 1 wave (all channels)
    cstr_mfma1_kernel<<<dim3(512), dim3(64), 0, stream>>>(
        useq, xGz0, W1, b1, W2, b2, W3, b3, out);
}